// Round 1
// baseline (2976.575 us; speedup 1.0000x reference)
//
#include <hip/hip_runtime.h>
#include <hip/hip_bf16.h>

#define LSDIM 30
#define BATCH 1024

__device__ __forceinline__ float lrelu(float v) { return v >= 0.0f ? v : 0.01f * v; }

// ---------------- Fused encoder: conv1..conv4 + FC + reparam ----------------
// grid = 1024 blocks (one image), 256 threads
__global__ __launch_bounds__(256) void encoder_kernel(
    const float* __restrict__ x, const float* __restrict__ eps,
    const float* __restrict__ w1, const float* __restrict__ b1,
    const float* __restrict__ w2, const float* __restrict__ b2,
    const float* __restrict__ w3, const float* __restrict__ b3,
    const float* __restrict__ w4, const float* __restrict__ b4,
    const float* __restrict__ mw, const float* __restrict__ mb,
    const float* __restrict__ vw, const float* __restrict__ vb,
    float* __restrict__ out_mu, float* __restrict__ out_lv, float* __restrict__ out_z,
    float* __restrict__ ws_z)
{
  __shared__ float xs[784];
  __shared__ float h1[8 * 169];   // pooled conv1: [8][13][13]
  __shared__ float h2[16 * 36];   // pooled conv2: [16][6][6]
  __shared__ float h3[32 * 16];   // conv3: [32][4][4]
  __shared__ float flat[256];     // conv4: [64][2][2] == flat layout
  __shared__ float mlv[60];

  const int b = blockIdx.x;
  const int tid = threadIdx.x;

  const float* xb = x + b * 784;
  for (int i = tid; i < 784; i += 256) xs[i] = xb[i];
  __syncthreads();

  // conv1 3x3 (1->8), lrelu, pool2 -> [8][13][13]
  for (int idx = tid; idx < 8 * 169; idx += 256) {
    int c = idx / 169, r = idx % 169;
    int py = r / 13, px = r % 13;
    float wv[9];
#pragma unroll
    for (int t = 0; t < 9; ++t) wv[t] = w1[c * 9 + t];
    float bias = b1[c];
    float m = -1e30f;
#pragma unroll
    for (int dy = 0; dy < 2; ++dy)
#pragma unroll
      for (int dx = 0; dx < 2; ++dx) {
        int oy = 2 * py + dy, ox = 2 * px + dx;  // 0..25
        float acc = bias;
#pragma unroll
        for (int ky = 0; ky < 3; ++ky)
#pragma unroll
          for (int kx = 0; kx < 3; ++kx)
            acc = fmaf(wv[ky * 3 + kx], xs[(oy + ky) * 28 + ox + kx], acc);
        m = fmaxf(m, lrelu(acc));
      }
    h1[idx] = m;
  }
  __syncthreads();

  // conv2 2x2 (8->16), lrelu, pool2: 13x13 -> 12x12 -> [16][6][6]
  for (int idx = tid; idx < 16 * 36; idx += 256) {
    int c = idx / 36, r = idx % 36;
    int py = r / 6, px = r % 6;
    float bias = b2[c];
    float m = -1e30f;
#pragma unroll
    for (int dy = 0; dy < 2; ++dy)
#pragma unroll
      for (int dx = 0; dx < 2; ++dx) {
        int oy = 2 * py + dy, ox = 2 * px + dx;  // 0..11
        float acc = bias;
        for (int ic = 0; ic < 8; ++ic) {
#pragma unroll
          for (int ky = 0; ky < 2; ++ky)
#pragma unroll
            for (int kx = 0; kx < 2; ++kx)
              acc = fmaf(w2[((c * 8 + ic) * 2 + ky) * 2 + kx],
                         h1[ic * 169 + (oy + ky) * 13 + ox + kx], acc);
        }
        m = fmaxf(m, lrelu(acc));
      }
    h2[idx] = m;
  }
  __syncthreads();

  // conv3 3x3 (16->32), lrelu: 6x6 -> [32][4][4]
  for (int idx = tid; idx < 32 * 16; idx += 256) {
    int c = idx / 16, r = idx % 16;
    int y = r / 4, xq = r % 4;
    float acc = b3[c];
    for (int ic = 0; ic < 16; ++ic) {
#pragma unroll
      for (int ky = 0; ky < 3; ++ky)
#pragma unroll
        for (int kx = 0; kx < 3; ++kx)
          acc = fmaf(w3[((c * 16 + ic) * 3 + ky) * 3 + kx],
                     h2[ic * 36 + (y + ky) * 6 + xq + kx], acc);
    }
    h3[idx] = lrelu(acc);
  }
  __syncthreads();

  // conv4 3x3 (32->64), lrelu: 4x4 -> [64][2][2] -> flat[256]
  {
    int c = tid >> 2, r = tid & 3;
    int y = r >> 1, xq = r & 1;
    float acc = b4[c];
    for (int ic = 0; ic < 32; ++ic) {
#pragma unroll
      for (int ky = 0; ky < 3; ++ky)
#pragma unroll
        for (int kx = 0; kx < 3; ++kx)
          acc = fmaf(w4[((c * 32 + ic) * 3 + ky) * 3 + kx],
                     h3[ic * 16 + (y + ky) * 4 + xq + kx], acc);
    }
    flat[tid] = lrelu(acc);  // flat index = c*4 + y*2 + x = tid
  }
  __syncthreads();

  // FC: mu (30x256), logvar (30x256)
  if (tid < 60) {
    int j = tid < 30 ? tid : tid - 30;
    const float* W = tid < 30 ? mw : vw;
    float acc = (tid < 30 ? mb[j] : vb[j]);
    for (int k = 0; k < 256; ++k) acc = fmaf(W[j * 256 + k], flat[k], acc);
    mlv[tid] = acc;
  }
  __syncthreads();

  if (tid < LSDIM) {
    float mu = mlv[tid], lv = mlv[30 + tid];
    float z = fmaf(eps[b * LSDIM + tid], expf(0.5f * lv), mu);
    out_mu[b * LSDIM + tid] = mu;
    out_lv[b * LSDIM + tid] = lv;
    out_z[b * LSDIM + tid] = z;
    ws_z[b * LSDIM + tid] = z;
  }
}

// ---------------- Decoder direct conv helper ----------------
// s_in: [CIN][6 rows][32 cols] padded to stride 208 floats per channel.
// Thread computes one output row (28 cols) of one output channel.
// All 64 lanes of a wave read the SAME LDS address (broadcast, conflict-free).
template <int CIN>
__device__ __forceinline__ void conv_rows(const float* __restrict__ s_in,
                                          const float* __restrict__ w,
                                          float bias_c, int c, int r, float acc[28])
{
#pragma unroll
  for (int xx = 0; xx < 28; ++xx) acc[xx] = bias_c;
  for (int ic = 0; ic < CIN; ++ic) {
    const float* wp = w + (c * CIN + ic) * 9;
    float wv[9];
#pragma unroll
    for (int t = 0; t < 9; ++t) wv[t] = wp[t];
    const float* srow = s_in + ic * 208;
#pragma unroll
    for (int ky = 0; ky < 3; ++ky) {
      float rowv[32];
      const float4* rp = (const float4*)(srow + (r + ky) * 32);
#pragma unroll
      for (int q = 0; q < 8; ++q) ((float4*)rowv)[q] = rp[q];
#pragma unroll
      for (int xx = 0; xx < 28; ++xx)
        acc[xx] = fmaf(wv[ky * 3 + 2], rowv[xx + 2],
                  fmaf(wv[ky * 3 + 1], rowv[xx + 1],
                  fmaf(wv[ky * 3 + 0], rowv[xx], acc[xx])));
    }
  }
}

// ---------------- conv5: synth input (x-plane, y-plane, z broadcast) ----------------
// grid = 1024*7 blocks (image, 4-row strip), 256 threads = 64 ch x 4 rows
__global__ __launch_bounds__(256) void dec_conv5(
    const float* __restrict__ zbuf, const float* __restrict__ w,
    const float* __restrict__ bias, __hip_bfloat16* __restrict__ out)
{
  __shared__ float s_in[32 * 208];
  const int blk = blockIdx.x;
  const int b = blk / 7, r0 = (blk % 7) * 4;
  const int tid = threadIdx.x;

  for (int idx = tid; idx < 32 * 192; idx += 256) {
    int c = idx & 31, pos = idx >> 5;
    int row = pos >> 5, col = pos & 31;
    int gy = r0 - 1 + row, gx = col - 1;
    float v = 0.0f;
    if ((unsigned)gy < 28u && (unsigned)gx < 28u) {
      if (c == 0)       v = fmaf((float)gy, 2.0f / 27.0f, -1.0f);
      else if (c == 1)  v = fmaf((float)gx, 2.0f / 27.0f, -1.0f);
      else              v = zbuf[b * LSDIM + (c - 2)];
    }
    s_in[c * 208 + row * 32 + col] = v;
  }
  __syncthreads();

  const int c = tid & 63, r = tid >> 6;
  float acc[28];
  conv_rows<32>(s_in, w, bias[c], c, r, acc);

  const int y = r0 + r;
  __hip_bfloat16* op = out + ((b * 28 + y) * 28) * 64 + c;
#pragma unroll
  for (int xx = 0; xx < 28; ++xx) op[xx * 64] = __float2bfloat16(lrelu(acc[xx]));
}

// ---------------- conv6/7/8 (64->64), optional fused conv9 (1x1) ----------------
// Intermediate activations: bf16 NHWC [b][y][x][c]
template <bool FUSE9>
__global__ __launch_bounds__(256) void dec_conv64(
    const __hip_bfloat16* __restrict__ in, const float* __restrict__ w,
    const float* __restrict__ bias, __hip_bfloat16* __restrict__ out,
    const float* __restrict__ w9, const float* __restrict__ b9,
    float* __restrict__ dout)
{
  __shared__ float s_in[64 * 208];  // 53.2 KB
  const int blk = blockIdx.x;
  const int b = blk / 7, r0 = (blk % 7) * 4;
  const int tid = threadIdx.x;

  for (int idx = tid; idx < 64 * 192; idx += 256) {
    int c = idx & 63, pos = idx >> 6;
    int row = pos >> 5, col = pos & 31;
    int gy = r0 - 1 + row, gx = col - 1;
    float v = 0.0f;
    if ((unsigned)gy < 28u && (unsigned)gx < 28u)
      v = __bfloat162float(in[((b * 28 + gy) * 28 + gx) * 64 + c]);
    s_in[c * 208 + row * 32 + col] = v;
  }
  __syncthreads();

  const int c = tid & 63, r = tid >> 6;
  float acc[28];
  conv_rows<64>(s_in, w, bias[c], c, r, acc);
#pragma unroll
  for (int xx = 0; xx < 28; ++xx) acc[xx] = lrelu(acc[xx]);

  if (!FUSE9) {
    const int y = r0 + r;
    __hip_bfloat16* op = out + ((b * 28 + y) * 28) * 64 + c;
#pragma unroll
    for (int xx = 0; xx < 28; ++xx) op[xx * 64] = __float2bfloat16(acc[xx]);
  } else {
    __syncthreads();  // all staging reads done; reuse s_in as output tile
    float* s_out = s_in;
#pragma unroll
    for (int xx = 0; xx < 28; ++xx) s_out[c * 112 + r * 28 + xx] = acc[xx];
    __syncthreads();
    if (tid < 112) {
      float a9 = b9[0];
      for (int cc = 0; cc < 64; ++cc) a9 = fmaf(w9[cc], s_out[cc * 112 + tid], a9);
      dout[b * 784 + r0 * 28 + tid] = lrelu(a9);
    }
  }
}

extern "C" void kernel_launch(void* const* d_in, const int* in_sizes, int n_in,
                              void* d_out, int out_size, void* d_ws, size_t ws_size,
                              hipStream_t stream)
{
  const float* x   = (const float*)d_in[0];
  const float* eps = (const float*)d_in[1];
  const float* w1 = (const float*)d_in[2];  const float* b1 = (const float*)d_in[3];
  const float* w2 = (const float*)d_in[4];  const float* b2 = (const float*)d_in[5];
  const float* w3 = (const float*)d_in[6];  const float* b3 = (const float*)d_in[7];
  const float* w4 = (const float*)d_in[8];  const float* b4 = (const float*)d_in[9];
  const float* mw = (const float*)d_in[10]; const float* mb = (const float*)d_in[11];
  const float* vw = (const float*)d_in[12]; const float* vb = (const float*)d_in[13];
  const float* w5 = (const float*)d_in[14]; const float* b5 = (const float*)d_in[15];
  const float* w6 = (const float*)d_in[16]; const float* b6 = (const float*)d_in[17];
  const float* w7 = (const float*)d_in[18]; const float* b7 = (const float*)d_in[19];
  const float* w8 = (const float*)d_in[20]; const float* b8 = (const float*)d_in[21];
  const float* w9 = (const float*)d_in[22]; const float* b9 = (const float*)d_in[23];

  float* dout   = (float*)d_out;
  float* out_mu = dout + 802816;   // 1024*784
  float* out_lv = dout + 833536;
  float* out_z  = dout + 864256;

  char* ws = (char*)d_ws;
  float* ws_z = (float*)ws;                                      // 1024*30 f32
  __hip_bfloat16* bufA = (__hip_bfloat16*)(ws + 131072);         // 1024*784*64 bf16
  __hip_bfloat16* bufB = (__hip_bfloat16*)(ws + 131072 + 102760448);

  encoder_kernel<<<1024, 256, 0, stream>>>(x, eps, w1, b1, w2, b2, w3, b3, w4, b4,
                                           mw, mb, vw, vb, out_mu, out_lv, out_z, ws_z);
  dec_conv5<<<1024 * 7, 256, 0, stream>>>(ws_z, w5, b5, bufA);
  dec_conv64<false><<<1024 * 7, 256, 0, stream>>>(bufA, w6, b6, bufB, nullptr, nullptr, nullptr);
  dec_conv64<false><<<1024 * 7, 256, 0, stream>>>(bufB, w7, b7, bufA, nullptr, nullptr, nullptr);
  dec_conv64<true ><<<1024 * 7, 256, 0, stream>>>(bufA, w8, b8, nullptr, w9, b9, dout);
}

// Round 2
// 594.372 us; speedup vs baseline: 5.0079x; 5.0079x over previous
//
#include <hip/hip_runtime.h>
#include <hip/hip_bf16.h>

#define LSDIM 30

typedef __attribute__((ext_vector_type(8))) short short8;
typedef __attribute__((ext_vector_type(4))) float f32x4;

__device__ __forceinline__ float lrelu(float v) { return v >= 0.0f ? v : 0.01f * v; }

// ---------------- Fused encoder: conv1..conv4 + FC + reparam ----------------
__global__ __launch_bounds__(256) void encoder_kernel(
    const float* __restrict__ x, const float* __restrict__ eps,
    const float* __restrict__ w1, const float* __restrict__ b1,
    const float* __restrict__ w2, const float* __restrict__ b2,
    const float* __restrict__ w3, const float* __restrict__ b3,
    const float* __restrict__ w4, const float* __restrict__ b4,
    const float* __restrict__ mw, const float* __restrict__ mb,
    const float* __restrict__ vw, const float* __restrict__ vb,
    float* __restrict__ out_mu, float* __restrict__ out_lv, float* __restrict__ out_z,
    float* __restrict__ ws_z)
{
  __shared__ float xs[784];
  __shared__ float h1[8 * 169];
  __shared__ float h2[16 * 36];
  __shared__ float h3[32 * 16];
  __shared__ float flat[256];
  __shared__ float mlv[60];

  const int b = blockIdx.x;
  const int tid = threadIdx.x;

  const float* xb = x + b * 784;
  for (int i = tid; i < 784; i += 256) xs[i] = xb[i];
  __syncthreads();

  for (int idx = tid; idx < 8 * 169; idx += 256) {
    int c = idx / 169, r = idx % 169;
    int py = r / 13, px = r % 13;
    float wv[9];
#pragma unroll
    for (int t = 0; t < 9; ++t) wv[t] = w1[c * 9 + t];
    float bias = b1[c];
    float m = -1e30f;
#pragma unroll
    for (int dy = 0; dy < 2; ++dy)
#pragma unroll
      for (int dx = 0; dx < 2; ++dx) {
        int oy = 2 * py + dy, ox = 2 * px + dx;
        float acc = bias;
#pragma unroll
        for (int ky = 0; ky < 3; ++ky)
#pragma unroll
          for (int kx = 0; kx < 3; ++kx)
            acc = fmaf(wv[ky * 3 + kx], xs[(oy + ky) * 28 + ox + kx], acc);
        m = fmaxf(m, lrelu(acc));
      }
    h1[idx] = m;
  }
  __syncthreads();

  for (int idx = tid; idx < 16 * 36; idx += 256) {
    int c = idx / 36, r = idx % 36;
    int py = r / 6, px = r % 6;
    float bias = b2[c];
    float m = -1e30f;
#pragma unroll
    for (int dy = 0; dy < 2; ++dy)
#pragma unroll
      for (int dx = 0; dx < 2; ++dx) {
        int oy = 2 * py + dy, ox = 2 * px + dx;
        float acc = bias;
        for (int ic = 0; ic < 8; ++ic) {
#pragma unroll
          for (int ky = 0; ky < 2; ++ky)
#pragma unroll
            for (int kx = 0; kx < 2; ++kx)
              acc = fmaf(w2[((c * 8 + ic) * 2 + ky) * 2 + kx],
                         h1[ic * 169 + (oy + ky) * 13 + ox + kx], acc);
        }
        m = fmaxf(m, lrelu(acc));
      }
    h2[idx] = m;
  }
  __syncthreads();

  for (int idx = tid; idx < 32 * 16; idx += 256) {
    int c = idx / 16, r = idx % 16;
    int y = r / 4, xq = r % 4;
    float acc = b3[c];
    for (int ic = 0; ic < 16; ++ic) {
#pragma unroll
      for (int ky = 0; ky < 3; ++ky)
#pragma unroll
        for (int kx = 0; kx < 3; ++kx)
          acc = fmaf(w3[((c * 16 + ic) * 3 + ky) * 3 + kx],
                     h2[ic * 36 + (y + ky) * 6 + xq + kx], acc);
    }
    h3[idx] = lrelu(acc);
  }
  __syncthreads();

  {
    int c = tid >> 2, r = tid & 3;
    int y = r >> 1, xq = r & 1;
    float acc = b4[c];
    for (int ic = 0; ic < 32; ++ic) {
#pragma unroll
      for (int ky = 0; ky < 3; ++ky)
#pragma unroll
        for (int kx = 0; kx < 3; ++kx)
          acc = fmaf(w4[((c * 32 + ic) * 3 + ky) * 3 + kx],
                     h3[ic * 16 + (y + ky) * 4 + xq + kx], acc);
    }
    flat[tid] = lrelu(acc);
  }
  __syncthreads();

  if (tid < 60) {
    int j = tid < 30 ? tid : tid - 30;
    const float* W = tid < 30 ? mw : vw;
    float acc = (tid < 30 ? mb[j] : vb[j]);
    for (int k = 0; k < 256; ++k) acc = fmaf(W[j * 256 + k], flat[k], acc);
    mlv[tid] = acc;
  }
  __syncthreads();

  if (tid < LSDIM) {
    float mu = mlv[tid], lv = mlv[30 + tid];
    float z = fmaf(eps[b * LSDIM + tid], expf(0.5f * lv), mu);
    out_mu[b * LSDIM + tid] = mu;
    out_lv[b * LSDIM + tid] = lv;
    out_z[b * LSDIM + tid] = z;
    ws_z[b * LSDIM + tid] = z;
  }
}

// ---------------- Weight repack: OIHW fp32 -> B-fragment-ordered bf16 ----------------
// wb[((nt*nks + ks)*64 + lane)*8 + e] = W[k][n],  k = ks*32 + ((lane>>4)&3)*8 + e,
// n = nt*16 + (lane&15), k = (dy*3+dx)*CIN + ic
__global__ __launch_bounds__(256) void repack_w(
    const float* __restrict__ w, __hip_bfloat16* __restrict__ wb, int CIN, int nks)
{
  int i = blockIdx.x * 256 + threadIdx.x;
  int total = 4 * nks * 64 * 8;
  if (i >= total) return;
  int e = i & 7, l = (i >> 3) & 63;
  int ksnt = i >> 9;
  int ks = ksnt % nks, nt = ksnt / nks;
  int k = ks * 32 + ((l >> 4) & 3) * 8 + e;
  int n = nt * 16 + (l & 15);
  int d = k / CIN, ic = k % CIN;
  int dy = d / 3, dx = d % 3;
  wb[i] = __float2bfloat16(w[((n * CIN + ic) * 3 + dy) * 3 + dx]);
}

// ---------------- Decoder conv via MFMA implicit GEMM ----------------
// Block: 512 thr = 8 waves = 4 rows (mg) x 2 N-halves (nh). Grid: 1024*7.
// Wave: row y0+mg, 2 M-tiles (x0=0,16), n-tiles {2nh, 2nh+1}. B-frags in regs.
template <int CIN, bool SYNTH, bool FUSE9>
__global__ __launch_bounds__(512, 2) void dec_mfma(
    const __hip_bfloat16* __restrict__ in, const float* __restrict__ zbuf,
    const __hip_bfloat16* __restrict__ wb, const float* __restrict__ bias,
    __hip_bfloat16* __restrict__ out,
    const float* __restrict__ w9, const float* __restrict__ b9,
    float* __restrict__ dout)
{
  constexpr int NKS = CIN * 9 / 32;           // 9 (CIN=32) or 18 (CIN=64)
  constexpr int SMEMB = 6 * 34 * CIN * 2;     // 13056 or 26112 bytes
  __shared__ __align__(16) char smem[SMEMB];
  __shared__ float zl[32];
  __shared__ float red[256];

  const int blk = blockIdx.x;
  const int b = blk / 7, y0 = (blk % 7) * 4;
  const int tid = threadIdx.x;
  const int lane = tid & 63;
  const int wv = tid >> 6;
  const int mg = wv >> 1, nh = wv & 1;
  const int lg = (lane >> 4) & 3;
  const int ml = lane & 15;

  // ---- load register-resident B fragments (coalesced dwordx4) ----
  short8 Bf[NKS][2];
  const short8* wbp = (const short8*)wb;
#pragma unroll
  for (int ks = 0; ks < NKS; ++ks) {
#pragma unroll
    for (int t = 0; t < 2; ++t)
      Bf[ks][t] = wbp[((2 * nh + t) * NKS + ks) * 64 + lane];
  }

  if constexpr (SYNTH) {
    if (tid < LSDIM) zl[tid] = zbuf[b * LSDIM + tid];
    __syncthreads();
  }

  // ---- stage padded input strip [6][34][CIN] bf16, XOR-swizzled ----
  constexpr int CH = CIN / 8;
  constexpr int NCHUNK = 6 * 34 * CH;
  for (int idx = tid; idx < NCHUNK; idx += 512) {
    int pos = idx / CH, icq = idx % CH;
    int r = pos / 34, j = pos % 34;
    int gy = y0 - 1 + r, gx = j - 1;
    int ic0 = icq * 8;
    short8 v = {0, 0, 0, 0, 0, 0, 0, 0};
    bool inr = ((unsigned)gy < 28u) && ((unsigned)gx < 28u);
    if constexpr (!SYNTH) {
      if (inr) v = *(const short8*)(in + ((b * 28 + gy) * 28 + gx) * CIN + ic0);
    } else {
      if (inr) {
#pragma unroll
        for (int e = 0; e < 8; ++e) {
          int c = ic0 + e;
          float f = (c == 0) ? fmaf((float)gy, 2.0f / 27.0f, -1.0f)
                  : (c == 1) ? fmaf((float)gx, 2.0f / 27.0f, -1.0f)
                  : zl[c - 2];
          __hip_bfloat16 h = __float2bfloat16(f);
          v[e] = __builtin_bit_cast(short, h);
        }
      }
    }
    int addr = (pos * CIN + ic0) * 2;
    if (CIN == 64) addr ^= (pos & 7) << 4;
    else           addr ^= ((pos >> 1) & 3) << 4;
    *(short8*)(smem + addr) = v;
  }
  __syncthreads();

  // ---- K-loop: 2 M-tiles x NKS K-steps, 2 MFMA per A-read ----
  f32x4 acc[2][2];
  {
    f32x4 z4 = {0.f, 0.f, 0.f, 0.f};
    acc[0][0] = z4; acc[0][1] = z4; acc[1][0] = z4; acc[1][1] = z4;
  }
#pragma unroll
  for (int mt = 0; mt < 2; ++mt) {
#pragma unroll
    for (int ks = 0; ks < NKS; ++ks) {
      const int k0 = ks * 32;
      const int d = k0 / CIN;
      const int dy = d / 3, dx = d % 3;
      const int icbase = k0 % CIN;
      int j = mt * 16 + ml + dx;
      int pos = (mg + dy) * 34 + j;
      int ic0 = icbase + lg * 8;
      int addr = (pos * CIN + ic0) * 2;
      if (CIN == 64) addr ^= (pos & 7) << 4;
      else           addr ^= ((pos >> 1) & 3) << 4;
      short8 A = *(const short8*)(smem + addr);
      acc[mt][0] = __builtin_amdgcn_mfma_f32_16x16x32_bf16(A, Bf[ks][0], acc[mt][0], 0, 0, 0);
      acc[mt][1] = __builtin_amdgcn_mfma_f32_16x16x32_bf16(A, Bf[ks][1], acc[mt][1], 0, 0, 0);
    }
  }

  // ---- epilogue ----
  const int y = y0 + mg;
  const int n0 = (2 * nh) * 16 + ml, n1 = n0 + 16;
  const float bb0 = bias[n0], bb1 = bias[n1];

  if constexpr (!FUSE9) {
#pragma unroll
    for (int mt = 0; mt < 2; ++mt) {
#pragma unroll
      for (int reg = 0; reg < 4; ++reg) {
        int xx = mt * 16 + lg * 4 + reg;
        if (xx < 28) {
          int base = ((b * 28 + y) * 28 + xx) * 64;
          out[base + n0] = __float2bfloat16(lrelu(acc[mt][0][reg] + bb0));
          out[base + n1] = __float2bfloat16(lrelu(acc[mt][1][reg] + bb1));
        }
      }
    }
  } else {
    const float w90 = w9[n0], w91 = w9[n1];
#pragma unroll
    for (int mt = 0; mt < 2; ++mt) {
#pragma unroll
      for (int reg = 0; reg < 4; ++reg) {
        float v0 = lrelu(acc[mt][0][reg] + bb0);
        float v1 = lrelu(acc[mt][1][reg] + bb1);
        float p = v0 * w90 + v1 * w91;
        p += __shfl_xor(p, 1);
        p += __shfl_xor(p, 2);
        p += __shfl_xor(p, 4);
        p += __shfl_xor(p, 8);
        if (ml == 0) red[(mg * 32 + mt * 16 + lg * 4 + reg) * 2 + nh] = p;
      }
    }
    __syncthreads();
    if (tid < 128) {
      int row = tid >> 5, xx = tid & 31;
      if (xx < 28) {
        float o = lrelu(b9[0] + red[tid * 2] + red[tid * 2 + 1]);
        dout[b * 784 + (y0 + row) * 28 + xx] = o;
      }
    }
  }
}

extern "C" void kernel_launch(void* const* d_in, const int* in_sizes, int n_in,
                              void* d_out, int out_size, void* d_ws, size_t ws_size,
                              hipStream_t stream)
{
  const float* x   = (const float*)d_in[0];
  const float* eps = (const float*)d_in[1];
  const float* w1 = (const float*)d_in[2];  const float* b1 = (const float*)d_in[3];
  const float* w2 = (const float*)d_in[4];  const float* b2 = (const float*)d_in[5];
  const float* w3 = (const float*)d_in[6];  const float* b3 = (const float*)d_in[7];
  const float* w4 = (const float*)d_in[8];  const float* b4 = (const float*)d_in[9];
  const float* mw = (const float*)d_in[10]; const float* mb = (const float*)d_in[11];
  const float* vw = (const float*)d_in[12]; const float* vb = (const float*)d_in[13];
  const float* w5 = (const float*)d_in[14]; const float* b5 = (const float*)d_in[15];
  const float* w6 = (const float*)d_in[16]; const float* b6 = (const float*)d_in[17];
  const float* w7 = (const float*)d_in[18]; const float* b7 = (const float*)d_in[19];
  const float* w8 = (const float*)d_in[20]; const float* b8 = (const float*)d_in[21];
  const float* w9 = (const float*)d_in[22]; const float* b9 = (const float*)d_in[23];

  float* dout   = (float*)d_out;
  float* out_mu = dout + 802816;
  float* out_lv = dout + 833536;
  float* out_z  = dout + 864256;

  char* ws = (char*)d_ws;
  float* ws_z = (float*)ws;                                     // 122880 B
  __hip_bfloat16* wb5 = (__hip_bfloat16*)(ws + 122880);         // 36864 B
  __hip_bfloat16* wb6 = (__hip_bfloat16*)(ws + 159744);         // 73728 B
  __hip_bfloat16* wb7 = (__hip_bfloat16*)(ws + 233472);         // 73728 B
  __hip_bfloat16* wb8 = (__hip_bfloat16*)(ws + 307200);         // 73728 B
  __hip_bfloat16* bufA = (__hip_bfloat16*)(ws + 380928);        // 102760448 B
  __hip_bfloat16* bufB = (__hip_bfloat16*)(ws + 380928 + 102760448);

  encoder_kernel<<<1024, 256, 0, stream>>>(x, eps, w1, b1, w2, b2, w3, b3, w4, b4,
                                           mw, mb, vw, vb, out_mu, out_lv, out_z, ws_z);

  repack_w<<<72, 256, 0, stream>>>(w5, wb5, 32, 9);
  repack_w<<<144, 256, 0, stream>>>(w6, wb6, 64, 18);
  repack_w<<<144, 256, 0, stream>>>(w7, wb7, 64, 18);
  repack_w<<<144, 256, 0, stream>>>(w8, wb8, 64, 18);

  dec_mfma<32, true, false><<<1024 * 7, 512, 0, stream>>>(
      nullptr, ws_z, wb5, b5, bufA, nullptr, nullptr, nullptr);
  dec_mfma<64, false, false><<<1024 * 7, 512, 0, stream>>>(
      bufA, nullptr, wb6, b6, bufB, nullptr, nullptr, nullptr);
  dec_mfma<64, false, false><<<1024 * 7, 512, 0, stream>>>(
      bufB, nullptr, wb7, b7, bufA, nullptr, nullptr, nullptr);
  dec_mfma<64, false, true><<<1024 * 7, 512, 0, stream>>>(
      bufA, nullptr, wb8, b8, nullptr, w9, b9, dout);
}

// Round 3
// 309.346 us; speedup vs baseline: 9.6221x; 1.9214x over previous
//
#include <hip/hip_runtime.h>
#include <hip/hip_bf16.h>

#define LSDIM 30

typedef __attribute__((ext_vector_type(8))) short short8;
typedef __attribute__((ext_vector_type(4))) float f32x4;

__device__ __forceinline__ float lrelu(float v) { return v >= 0.0f ? v : 0.01f * v; }

// ---------------- Fused encoder: conv1..conv4 + FC + reparam ----------------
__global__ __launch_bounds__(256) void encoder_kernel(
    const float* __restrict__ x, const float* __restrict__ eps,
    const float* __restrict__ w1, const float* __restrict__ b1,
    const float* __restrict__ w2, const float* __restrict__ b2,
    const float* __restrict__ w3, const float* __restrict__ b3,
    const float* __restrict__ w4, const float* __restrict__ b4,
    const float* __restrict__ mw, const float* __restrict__ mb,
    const float* __restrict__ vw, const float* __restrict__ vb,
    float* __restrict__ out_mu, float* __restrict__ out_lv, float* __restrict__ out_z,
    float* __restrict__ ws_z)
{
  __shared__ float xs[784];
  __shared__ float h1[8 * 169];
  __shared__ float h2[16 * 36];
  __shared__ float h3[32 * 16];
  __shared__ float flat[256];
  __shared__ float mlv[60];

  const int b = blockIdx.x;
  const int tid = threadIdx.x;

  const float* xb = x + b * 784;
  for (int i = tid; i < 784; i += 256) xs[i] = xb[i];
  __syncthreads();

  for (int idx = tid; idx < 8 * 169; idx += 256) {
    int c = idx / 169, r = idx % 169;
    int py = r / 13, px = r % 13;
    float wv[9];
#pragma unroll
    for (int t = 0; t < 9; ++t) wv[t] = w1[c * 9 + t];
    float bias = b1[c];
    float m = -1e30f;
#pragma unroll
    for (int dy = 0; dy < 2; ++dy)
#pragma unroll
      for (int dx = 0; dx < 2; ++dx) {
        int oy = 2 * py + dy, ox = 2 * px + dx;
        float acc = bias;
#pragma unroll
        for (int ky = 0; ky < 3; ++ky)
#pragma unroll
          for (int kx = 0; kx < 3; ++kx)
            acc = fmaf(wv[ky * 3 + kx], xs[(oy + ky) * 28 + ox + kx], acc);
        m = fmaxf(m, lrelu(acc));
      }
    h1[idx] = m;
  }
  __syncthreads();

  for (int idx = tid; idx < 16 * 36; idx += 256) {
    int c = idx / 36, r = idx % 36;
    int py = r / 6, px = r % 6;
    float bias = b2[c];
    float m = -1e30f;
#pragma unroll
    for (int dy = 0; dy < 2; ++dy)
#pragma unroll
      for (int dx = 0; dx < 2; ++dx) {
        int oy = 2 * py + dy, ox = 2 * px + dx;
        float acc = bias;
        for (int ic = 0; ic < 8; ++ic) {
#pragma unroll
          for (int ky = 0; ky < 2; ++ky)
#pragma unroll
            for (int kx = 0; kx < 2; ++kx)
              acc = fmaf(w2[((c * 8 + ic) * 2 + ky) * 2 + kx],
                         h1[ic * 169 + (oy + ky) * 13 + ox + kx], acc);
        }
        m = fmaxf(m, lrelu(acc));
      }
    h2[idx] = m;
  }
  __syncthreads();

  for (int idx = tid; idx < 32 * 16; idx += 256) {
    int c = idx / 16, r = idx % 16;
    int y = r / 4, xq = r % 4;
    float acc = b3[c];
    for (int ic = 0; ic < 16; ++ic) {
#pragma unroll
      for (int ky = 0; ky < 3; ++ky)
#pragma unroll
        for (int kx = 0; kx < 3; ++kx)
          acc = fmaf(w3[((c * 16 + ic) * 3 + ky) * 3 + kx],
                     h2[ic * 36 + (y + ky) * 6 + xq + kx], acc);
    }
    h3[idx] = lrelu(acc);
  }
  __syncthreads();

  {
    int c = tid >> 2, r = tid & 3;
    int y = r >> 1, xq = r & 1;
    float acc = b4[c];
    for (int ic = 0; ic < 32; ++ic) {
#pragma unroll
      for (int ky = 0; ky < 3; ++ky)
#pragma unroll
        for (int kx = 0; kx < 3; ++kx)
          acc = fmaf(w4[((c * 32 + ic) * 3 + ky) * 3 + kx],
                     h3[ic * 16 + (y + ky) * 4 + xq + kx], acc);
    }
    flat[tid] = lrelu(acc);
  }
  __syncthreads();

  if (tid < 60) {
    int j = tid < 30 ? tid : tid - 30;
    const float* W = tid < 30 ? mw : vw;
    float acc = (tid < 30 ? mb[j] : vb[j]);
    for (int k = 0; k < 256; ++k) acc = fmaf(W[j * 256 + k], flat[k], acc);
    mlv[tid] = acc;
  }
  __syncthreads();

  if (tid < LSDIM) {
    float mu = mlv[tid], lv = mlv[30 + tid];
    float z = fmaf(eps[b * LSDIM + tid], expf(0.5f * lv), mu);
    out_mu[b * LSDIM + tid] = mu;
    out_lv[b * LSDIM + tid] = lv;
    out_z[b * LSDIM + tid] = z;
    ws_z[b * LSDIM + tid] = z;
  }
}

// ---------------- Weight repack (all 4 decoder convs in one kernel) ----------------
// wb[((nt*nks + ks)*64 + l)*8 + e] = W[k][n], k = ks*32 + ((l>>4)&3)*8 + e,
// n = nt*16 + (l&15), k = (dy*3+dx)*CIN + ic
__global__ __launch_bounds__(256) void repack_all(
    const float* __restrict__ w5, const float* __restrict__ w6,
    const float* __restrict__ w7, const float* __restrict__ w8,
    __hip_bfloat16* __restrict__ wb5, __hip_bfloat16* __restrict__ wb6,
    __hip_bfloat16* __restrict__ wb7, __hip_bfloat16* __restrict__ wb8)
{
  int i = blockIdx.x * 256 + threadIdx.x;
  const float* w;
  __hip_bfloat16* wb;
  int CIN, nks, j;
  if (i < 18432)       { w = w5; wb = wb5; CIN = 32; nks = 9;  j = i; }
  else if (i < 55296)  { w = w6; wb = wb6; CIN = 64; nks = 18; j = i - 18432; }
  else if (i < 92160)  { w = w7; wb = wb7; CIN = 64; nks = 18; j = i - 55296; }
  else if (i < 129024) { w = w8; wb = wb8; CIN = 64; nks = 18; j = i - 92160; }
  else return;
  int e = j & 7, l = (j >> 3) & 63;
  int ksnt = j >> 9;
  int ks = ksnt % nks, nt = ksnt / nks;
  int k = ks * 32 + ((l >> 4) & 3) * 8 + e;
  int n = nt * 16 + (l & 15);
  int d = k / CIN, ic = k % CIN;
  int dy = d / 3, dx = d % 3;
  wb[j] = __float2bfloat16(w[((n * CIN + ic) * 3 + dy) * 3 + dx]);
}

// ---------------- One conv phase of the fused decoder ----------------
// Ring layout: slot s (0..31) x col j (0..31) x ch c (0..63) bf16, 128 B per (s,j),
// addr = (s*32+j)*128 + c*2, XOR-swizzled by (j&7)<<4.
// Input logical row r at slot OFF+r; halos (r=-1,28) at OFF-1, OFF+28 zeroed here.
// DOWN (UP=false): groups g=6..0, out row o -> slot OFF+o+2 (off' = OFF+2).
// UP:              groups g=0..6, out row o -> slot OFF+o-2 (off' = OFF-2).
template <int CIN, int OFF, bool UP, bool FUSE9>
__device__ __forceinline__ void conv_phase(
    char* __restrict__ smem, float* __restrict__ red, int b,
    const __hip_bfloat16* __restrict__ wb, const float* __restrict__ bias,
    const float* __restrict__ w9, const float* __restrict__ b9,
    float* __restrict__ dout)
{
  constexpr int NKS = CIN * 9 / 32;
  const int tid = threadIdx.x;
  const int lane = tid & 63, wv = tid >> 6;
  const int mg = wv >> 1, nh = wv & 1;
  const int lg = (lane >> 4) & 3, ml = lane & 15;

  // register-resident B fragments (loaded once per image per conv)
  short8 Bf[NKS][2];
  const short8* wbp = (const short8*)wb;
#pragma unroll
  for (int ks = 0; ks < NKS; ++ks)
#pragma unroll
    for (int t = 0; t < 2; ++t)
      Bf[ks][t] = wbp[((2 * nh + t) * NKS + ks) * 64 + lane];

  // zero the two halo slots (full 4 KB each; swizzle-invariant)
  {
    int s = (tid >= 256) ? (OFF + 28) : (OFF - 1);
    short8 z8 = {0, 0, 0, 0, 0, 0, 0, 0};
    ((short8*)(smem + s * 4096))[tid & 255] = z8;
  }
  __syncthreads();

  const float bb0 = bias[nh * 32 + ml], bb1 = bias[nh * 32 + 16 + ml];

  for (int gi = 0; gi < 7; ++gi) {
    const int g = UP ? gi : 6 - gi;
    const int orow = 4 * g + mg;
    f32x4 acc[2][2];
    {
      f32x4 zz = {0.f, 0.f, 0.f, 0.f};
      acc[0][0] = zz; acc[0][1] = zz; acc[1][0] = zz; acc[1][1] = zz;
    }
    const int rowbase = (OFF - 1 + orow) * 32;
#pragma unroll
    for (int mt = 0; mt < 2; ++mt) {
      const int xm = mt * 16 + ml;
#pragma unroll
      for (int ks = 0; ks < NKS; ++ks) {
        const int k0 = ks * 32;
        const int d = k0 / CIN;
        const int dy = d / 3, dx = d % 3;
        const int icb = k0 % CIN;
        const int j = (xm + dx) & 31;           // garbage lanes (x>=28) stay in-bounds
        const int pos = rowbase + dy * 32 + j;
        int addr = pos * 128 + (icb + lg * 8) * 2;
        addr ^= (j & 7) << 4;
        short8 A = *(const short8*)(smem + addr);
        acc[mt][0] = __builtin_amdgcn_mfma_f32_16x16x32_bf16(A, Bf[ks][0], acc[mt][0], 0, 0, 0);
        acc[mt][1] = __builtin_amdgcn_mfma_f32_16x16x32_bf16(A, Bf[ks][1], acc[mt][1], 0, 0, 0);
      }
    }

    if constexpr (!FUSE9) {
      __syncthreads();  // all reads of this group done before overwriting slots
      const int wslot = OFF + orow + (UP ? -2 : 2);
#pragma unroll
      for (int mt = 0; mt < 2; ++mt)
#pragma unroll
        for (int t = 0; t < 2; ++t) {
          const int n = (2 * nh + t) * 16 + ml;
          const float bb = t ? bb1 : bb0;
#pragma unroll
          for (int reg = 0; reg < 4; ++reg) {
            const int xx = mt * 16 + lg * 4 + reg;
            if (xx < 28) {
              const int j = xx + 1;
              const int pos = wslot * 32 + j;
              int addr = pos * 128 + n * 2;
              addr ^= (j & 7) << 4;
              *(__hip_bfloat16*)(smem + addr) = __float2bfloat16(lrelu(acc[mt][t][reg] + bb));
            }
          }
        }
      // zero pad cols 0 and 29 of the written row (next conv's x-halo)
      if (lg < 2) {
        const int j = lg ? 29 : 0;
        const int pos = wslot * 32 + j;
#pragma unroll
        for (int t = 0; t < 2; ++t) {
          const int n = (2 * nh + t) * 16 + ml;
          int addr = pos * 128 + n * 2;
          addr ^= (j & 7) << 4;
          *(__hip_bfloat16*)(smem + addr) = __float2bfloat16(0.0f);
        }
      }
    } else {
      // conv9 (1x1, 64->1) fused: dot over channels, wave-reduce, write f32 out
      const float w90 = w9[nh * 32 + ml], w91 = w9[nh * 32 + 16 + ml];
#pragma unroll
      for (int mt = 0; mt < 2; ++mt)
#pragma unroll
        for (int reg = 0; reg < 4; ++reg) {
          float v0 = lrelu(acc[mt][0][reg] + bb0);
          float v1 = lrelu(acc[mt][1][reg] + bb1);
          float p = v0 * w90 + v1 * w91;
          p += __shfl_xor(p, 1);
          p += __shfl_xor(p, 2);
          p += __shfl_xor(p, 4);
          p += __shfl_xor(p, 8);
          if (ml == 0) red[(mg * 32 + mt * 16 + lg * 4 + reg) * 2 + nh] = p;
        }
      __syncthreads();
      if (tid < 128) {
        const int row = tid >> 5, xx = tid & 31;
        if (xx < 28) {
          float o = lrelu(b9[0] + red[tid * 2] + red[tid * 2 + 1]);
          dout[b * 784 + (4 * g + row) * 28 + xx] = o;
        }
      }
      __syncthreads();  // before next group overwrites red
    }
  }
}

// ---------------- Fused decoder: synth + conv5..conv8 + conv9, all in LDS ----------------
__global__ __launch_bounds__(512, 2) void fused_decoder(
    const float* __restrict__ zbuf,
    const __hip_bfloat16* __restrict__ wb5, const float* __restrict__ b5,
    const __hip_bfloat16* __restrict__ wb6, const float* __restrict__ b6,
    const __hip_bfloat16* __restrict__ wb7, const float* __restrict__ b7,
    const __hip_bfloat16* __restrict__ wb8, const float* __restrict__ b8,
    const float* __restrict__ w9, const float* __restrict__ b9,
    float* __restrict__ dout)
{
  extern __shared__ __align__(16) char smem[];   // 131072 ring + 1024 red + 128 zl
  float* red = (float*)(smem + 131072);
  float* zl  = (float*)(smem + 132096);
  const int b = blockIdx.x;
  const int tid = threadIdx.x;

  if (tid < LSDIM) zl[tid] = zbuf[b * LSDIM + tid];
  __syncthreads();

  // synthesize conv5 input (ch0 = row-grid, ch1 = col-grid, ch2..31 = z) into
  // slots 1..28 (logical rows 0..27); 32-ch data in lower half of 64-ch blocks
  for (int idx = tid; idx < 28 * 32 * 4; idx += 512) {
    const int icq = idx & 3;
    const int j = (idx >> 2) & 31;
    const int r = idx >> 7;
    const int gx = j - 1;
    short8 v = {0, 0, 0, 0, 0, 0, 0, 0};
    if ((unsigned)gx < 28u) {
      const float gyv = fmaf((float)r, 2.0f / 27.0f, -1.0f);
      const float gxv = fmaf((float)gx, 2.0f / 27.0f, -1.0f);
#pragma unroll
      for (int e = 0; e < 8; ++e) {
        int c = icq * 8 + e;
        float f = (c == 0) ? gyv : (c == 1) ? gxv : zl[c - 2];
        v[e] = __builtin_bit_cast(short, __float2bfloat16(f));
      }
    }
    const int pos = (r + 1) * 32 + j;
    int addr = pos * 128 + icq * 16;
    addr ^= (j & 7) << 4;
    *(short8*)(smem + addr) = v;
  }
  // conv_phase starts with halo-zero (slots 0,29 — disjoint from synth writes)
  // followed by __syncthreads, which orders the synth writes before any read.

  conv_phase<32, 1, false, false>(smem, red, b, wb5, b5, nullptr, nullptr, nullptr);
  conv_phase<64, 3, true,  false>(smem, red, b, wb6, b6, nullptr, nullptr, nullptr);
  conv_phase<64, 1, false, false>(smem, red, b, wb7, b7, nullptr, nullptr, nullptr);
  conv_phase<64, 3, true,  true >(smem, red, b, wb8, b8, w9, b9, dout);
}

extern "C" void kernel_launch(void* const* d_in, const int* in_sizes, int n_in,
                              void* d_out, int out_size, void* d_ws, size_t ws_size,
                              hipStream_t stream)
{
  const float* x   = (const float*)d_in[0];
  const float* eps = (const float*)d_in[1];
  const float* w1 = (const float*)d_in[2];  const float* b1 = (const float*)d_in[3];
  const float* w2 = (const float*)d_in[4];  const float* b2 = (const float*)d_in[5];
  const float* w3 = (const float*)d_in[6];  const float* b3 = (const float*)d_in[7];
  const float* w4 = (const float*)d_in[8];  const float* b4 = (const float*)d_in[9];
  const float* mw = (const float*)d_in[10]; const float* mb = (const float*)d_in[11];
  const float* vw = (const float*)d_in[12]; const float* vb = (const float*)d_in[13];
  const float* w5 = (const float*)d_in[14]; const float* b5 = (const float*)d_in[15];
  const float* w6 = (const float*)d_in[16]; const float* b6 = (const float*)d_in[17];
  const float* w7 = (const float*)d_in[18]; const float* b7 = (const float*)d_in[19];
  const float* w8 = (const float*)d_in[20]; const float* b8 = (const float*)d_in[21];
  const float* w9 = (const float*)d_in[22]; const float* b9 = (const float*)d_in[23];

  float* dout   = (float*)d_out;
  float* out_mu = dout + 802816;
  float* out_lv = dout + 833536;
  float* out_z  = dout + 864256;

  char* ws = (char*)d_ws;
  float* ws_z = (float*)ws;                                  // 122880 B
  __hip_bfloat16* wb5 = (__hip_bfloat16*)(ws + 122880);      // 36864 B
  __hip_bfloat16* wb6 = (__hip_bfloat16*)(ws + 159744);      // 73728 B
  __hip_bfloat16* wb7 = (__hip_bfloat16*)(ws + 233472);      // 73728 B
  __hip_bfloat16* wb8 = (__hip_bfloat16*)(ws + 307200);      // 73728 B

  const int smem_bytes = 132224;
  (void)hipFuncSetAttribute((const void*)fused_decoder,
                            hipFuncAttributeMaxDynamicSharedMemorySize, smem_bytes);

  repack_all<<<504, 256, 0, stream>>>(w5, w6, w7, w8, wb5, wb6, wb7, wb8);
  encoder_kernel<<<1024, 256, 0, stream>>>(x, eps, w1, b1, w2, b2, w3, b3, w4, b4,
                                           mw, mb, vw, vb, out_mu, out_lv, out_z, ws_z);
  fused_decoder<<<1024, 512, smem_bytes, stream>>>(ws_z, wb5, b5, wb6, b6, wb7, b7,
                                                   wb8, b8, w9, b9, dout);
}